// Round 1
// baseline (6729.925 us; speedup 1.0000x reference)
//
#include <hip/hip_runtime.h>

// ---------------- kernels ----------------

static __global__ void k_fill(float* __restrict__ p, float v, int n) {
  int i = blockIdx.x * blockDim.x + threadIdx.x;
  if (i < n) p[i] = v;
}

static __global__ void k_deg(float* __restrict__ deg, const int* __restrict__ dst, int E) {
  int e = blockIdx.x * blockDim.x + threadIdx.x;
  if (e < E) atomicAdd(&deg[dst[e]], 1.0f);
}

static __global__ void k_rsqrt(float* __restrict__ d, int n) {
  int i = blockIdx.x * blockDim.x + threadIdx.x;
  if (i < n) d[i] = 1.0f / sqrtf(d[i]);
}

static __global__ void k_count(float* __restrict__ cnt, const int* __restrict__ batch, int n) {
  int i = blockIdx.x * blockDim.x + threadIdx.x;
  if (i < n) atomicAdd(&cnt[batch[i]], 1.0f);
}

// AG[i,k] = X[i,k] * dinv[i]^2   (self-loop term of the normalized adjacency)
static __global__ void k_self_init(float* __restrict__ AG, const float* __restrict__ X,
                                   const float* __restrict__ dinv, int n, int K) {
  int i = blockIdx.x * blockDim.x + threadIdx.x;
  int tot = n * K;
  if (i >= tot) return;
  int row = i / K;
  float dv = dinv[row];
  AG[i] = X[i] * dv * dv;
}

// AG[dst,k] += X[src,k] * dinv[src]*dinv[dst]  -- one block per edge
static __global__ void __launch_bounds__(128)
k_edge_scatter(float* __restrict__ AG, const float* __restrict__ X,
               const int* __restrict__ src, const int* __restrict__ dst,
               const float* __restrict__ dinv, int E, int K) {
  int e = blockIdx.x;
  if (e >= E) return;
  int s = src[e], d = dst[e];
  float w = dinv[s] * dinv[d];
  const float* xr = X + (size_t)s * K;
  float* ar = AG + (size_t)d * K;
  for (int k = threadIdx.x; k < K; k += blockDim.x)
    atomicAdd(&ar[k], xr[k] * w);
}

// Y = [relu](A @ W + b); POOL: atomically accumulate into pooled[batch[row]*ystride+col]
template<bool RELU, bool POOL>
static __global__ void __launch_bounds__(256)
k_gemm(const float* __restrict__ A, const float* __restrict__ W,
       const float* __restrict__ bias, float* __restrict__ Y,
       int n, int Kin, int Kout,
       const int* __restrict__ batch, int ystride) {
  int idx = blockIdx.x * blockDim.x + threadIdx.x;
  int tot = n * Kout;
  if (idx >= tot) return;
  int row = idx / Kout;
  int col = idx - row * Kout;
  const float* a = A + (size_t)row * Kin;
  const float* w = W + col;
  float acc = bias[col];
  for (int k = 0; k < Kin; ++k)
    acc = fmaf(a[k], w[(size_t)k * Kout], acc);
  if (RELU) acc = fmaxf(acc, 0.0f);
  if (POOL) atomicAdd(&Y[(size_t)batch[row] * ystride + col], acc);
  else      Y[(size_t)row * ystride + col] = acc;
}

// pooled[b, colbase+c] /= max(cnt[b],1)   over 512 graphs x 256 cols
static __global__ void k_pool_div(float* __restrict__ pooled, const float* __restrict__ cnt,
                                  int colbase) {
  int i = blockIdx.x * blockDim.x + threadIdx.x;
  if (i >= 512 * 256) return;
  int b = i >> 8;
  int c = i & 255;
  pooled[b * 512 + colbase + c] /= fmaxf(cnt[b], 1.0f);
}

// out[row] = X[row,:512] . w + b   -- one wave per row
static __global__ void k_out(float* __restrict__ out, const float* __restrict__ X,
                             const float* __restrict__ w, const float* __restrict__ b) {
  int row = blockIdx.x;
  int lane = threadIdx.x;
  float acc = 0.f;
  for (int k = lane; k < 512; k += 64)
    acc = fmaf(X[row * 512 + k], w[k], acc);
#pragma unroll
  for (int off = 32; off; off >>= 1) acc += __shfl_down(acc, off);
  if (lane == 0) out[row] = acc + b[0];
}

// ---------------- launch ----------------

extern "C" void kernel_launch(void* const* d_in, const int* in_sizes, int n_in,
                              void* d_out, int out_size, void* d_ws, size_t ws_size,
                              hipStream_t stream) {
  const float* p_x  = (const float*)d_in[0];
  const int*   p_ei = (const int*)d_in[1];
  const int*   p_bt = (const int*)d_in[2];
  const float* l_x  = (const float*)d_in[3];
  const int*   l_ei = (const int*)d_in[4];
  const int*   l_bt = (const int*)d_in[5];
  const float* pW1 = (const float*)d_in[6],  *pb1 = (const float*)d_in[7];
  const float* pW2 = (const float*)d_in[8],  *pb2 = (const float*)d_in[9];
  const float* pW3 = (const float*)d_in[10], *pb3 = (const float*)d_in[11];
  const float* lW1 = (const float*)d_in[12], *lb1 = (const float*)d_in[13];
  const float* lW2 = (const float*)d_in[14], *lb2 = (const float*)d_in[15];
  const float* lW3 = (const float*)d_in[16], *lb3 = (const float*)d_in[17];
  const float* fc1W = (const float*)d_in[18], *fc1b = (const float*)d_in[19];
  const float* fc2W = (const float*)d_in[20], *fc2b = (const float*)d_in[21];
  const float* oW  = (const float*)d_in[22], *ob  = (const float*)d_in[23];

  const int n_p = in_sizes[2], n_l = in_sizes[5];
  const int E_p = in_sizes[1] / 2, E_l = in_sizes[4] / 2;
  const int IN_P = in_sizes[0] / n_p, IN_L = in_sizes[3] / n_l;   // 41, 78

  char* wsc = (char*)d_ws;
  size_t off = 0;
  auto alloc = [&](size_t bytes) -> void* {
    void* p = wsc + off;
    off = (off + bytes + 255) & ~(size_t)255;
    return p;
  };
  float* dinv_p = (float*)alloc((size_t)n_p * 4);
  float* dinv_l = (float*)alloc((size_t)n_l * 4);
  float* cnt_p  = (float*)alloc(512 * 4);
  float* cnt_l  = (float*)alloc(512 * 4);
  float* pooled = (float*)alloc(512 * 512 * 4);
  float* F      = (float*)alloc((size_t)n_p * 128 * 4);
  float* AG     = (float*)alloc((size_t)n_p * 128 * 4);
  float* fc1o   = F;                 // branches are done before the FC stack
  float* fc2o   = F + 512 * 1024;
  (void)ws_size; (void)n_in; (void)out_size;

  hipMemsetAsync(pooled, 0, 512 * 512 * 4, stream);
  hipMemsetAsync(cnt_p, 0, 512 * 4, stream);
  hipMemsetAsync(cnt_l, 0, 512 * 4, stream);

  auto branch = [&](const float* x0, const int* ei, const int* batch, int n, int E, int IN,
                    const float* W1, const float* b1, const float* W2, const float* b2,
                    const float* W3, const float* b3, float* dinv, float* cnt, int colbase) {
    const int* src = ei;
    const int* dst = ei + E;
    k_fill<<<(n + 255) / 256, 256, 0, stream>>>(dinv, 1.0f, n);
    k_deg<<<(E + 255) / 256, 256, 0, stream>>>(dinv, dst, E);
    k_rsqrt<<<(n + 255) / 256, 256, 0, stream>>>(dinv, n);
    k_count<<<(n + 255) / 256, 256, 0, stream>>>(cnt, batch, n);
    // layer 1: AG = A_hat x0 ; F = relu(AG @ W1 + b1)   [n x 64]
    int tot = n * IN;
    k_self_init<<<(tot + 255) / 256, 256, 0, stream>>>(AG, x0, dinv, n, IN);
    k_edge_scatter<<<E, (IN + 63) / 64 * 64, 0, stream>>>(AG, x0, src, dst, dinv, E, IN);
    k_gemm<true, false><<<(n * 64 + 255) / 256, 256, 0, stream>>>(AG, W1, b1, F, n, IN, 64, nullptr, 64);
    // layer 2: AG = A_hat x1 ; F = relu(AG @ W2 + b2)   [n x 128]
    tot = n * 64;
    k_self_init<<<(tot + 255) / 256, 256, 0, stream>>>(AG, F, dinv, n, 64);
    k_edge_scatter<<<E, 64, 0, stream>>>(AG, F, src, dst, dinv, E, 64);
    k_gemm<true, false><<<(n * 128 + 255) / 256, 256, 0, stream>>>(AG, W2, b2, F, n, 64, 128, nullptr, 128);
    // layer 3: AG = A_hat x2 ; pooled[batch] += relu(AG @ W3 + b3)  (fused mean-pool numerator)
    tot = n * 128;
    k_self_init<<<(tot + 255) / 256, 256, 0, stream>>>(AG, F, dinv, n, 128);
    k_edge_scatter<<<E, 128, 0, stream>>>(AG, F, src, dst, dinv, E, 128);
    k_gemm<true, true><<<(n * 256 + 255) / 256, 256, 0, stream>>>(AG, W3, b3, pooled + colbase, n, 128, 256, batch, 512);
  };

  branch(p_x, p_ei, p_bt, n_p, E_p, IN_P, pW1, pb1, pW2, pb2, pW3, pb3, dinv_p, cnt_p, 0);
  branch(l_x, l_ei, l_bt, n_l, E_l, IN_L, lW1, lb1, lW2, lb2, lW3, lb3, dinv_l, cnt_l, 256);

  k_pool_div<<<(512 * 256 + 255) / 256, 256, 0, stream>>>(pooled, cnt_p, 0);
  k_pool_div<<<(512 * 256 + 255) / 256, 256, 0, stream>>>(pooled, cnt_l, 256);

  // FC stack
  k_gemm<true, false><<<(512 * 1024 + 255) / 256, 256, 0, stream>>>(pooled, fc1W, fc1b, fc1o, 512, 512, 1024, nullptr, 1024);
  k_gemm<true, false><<<(512 * 512 + 255) / 256, 256, 0, stream>>>(fc1o, fc2W, fc2b, fc2o, 512, 1024, 512, nullptr, 512);
  k_out<<<512, 64, 0, stream>>>((float*)d_out, fc2o, oW, ob);
}

// Round 3
// 2402.994 us; speedup vs baseline: 2.8006x; 2.8006x over previous
//
#include <hip/hip_runtime.h>

// ---------------- small helper kernels ----------------

static __global__ void k_fill(float* __restrict__ p, float v, int n) {
  int i = blockIdx.x * blockDim.x + threadIdx.x;
  if (i < n) p[i] = v;
}

static __global__ void k_deg(float* __restrict__ deg, const int* __restrict__ dst, int E) {
  int e = blockIdx.x * blockDim.x + threadIdx.x;
  if (e < E) atomicAdd(&deg[dst[e]], 1.0f);
}

static __global__ void k_rsqrt(float* __restrict__ d, int n) {
  int i = blockIdx.x * blockDim.x + threadIdx.x;
  if (i < n) d[i] = 1.0f / sqrtf(d[i]);
}

static __global__ void k_count(float* __restrict__ cnt, const int* __restrict__ batch, int n) {
  int i = blockIdx.x * blockDim.x + threadIdx.x;
  if (i < n) atomicAdd(&cnt[batch[i]], 1.0f);
}

// AG[i,k] = X[i,k] * dinv[i]^2   (self-loop term)
static __global__ void k_self_init(float* __restrict__ AG, const float* __restrict__ X,
                                   const float* __restrict__ dinv, int n, int K) {
  int i = blockIdx.x * blockDim.x + threadIdx.x;
  int tot = n * K;
  if (i >= tot) return;
  int row = i / K;
  float dv = dinv[row];
  AG[i] = X[i] * dv * dv;
}

// AG[dst,k] += X[src,k] * dinv[src]*dinv[dst]  -- one block per edge
static __global__ void __launch_bounds__(128)
k_edge_scatter(float* __restrict__ AG, const float* __restrict__ X,
               const int* __restrict__ src, const int* __restrict__ dst,
               const float* __restrict__ dinv, int E, int K) {
  int e = blockIdx.x;
  if (e >= E) return;
  int s = src[e], d = dst[e];
  float w = dinv[s] * dinv[d];
  const float* xr = X + (size_t)s * K;
  float* ar = AG + (size_t)d * K;
  for (int k = threadIdx.x; k < K; k += blockDim.x)
    atomicAdd(&ar[k], xr[k] * w);
}

// ---------------- tiled GEMM ----------------
// Y = [relu](A @ W + b).  Tile 64x64, 256 threads, 4x4 per thread, K-chunk 32.
// POOL: instead of storing Y rows, segment-sum rows by (sorted) batch and
// atomicAdd into Y[batch*ystride + colbase + col]  (the mean-pool numerator).
template<bool RELU, bool POOL>
static __global__ void __launch_bounds__(256)
k_gemm_t(const float* __restrict__ A, const float* __restrict__ W,
         const float* __restrict__ bias, float* __restrict__ Y,
         int n, int Kin, int Kout,
         const int* __restrict__ batch, int ystride, int colbase) {
  __shared__ float smem[2 * 32 * 68];
  float (*As)[68] = (float(*)[68])smem;             // As[k][row] (transposed)
  float (*Ws)[68] = (float(*)[68])(smem + 32 * 68); // Ws[k][col]

  const int tid = threadIdx.x;
  const int tx = tid & 15, ty = tid >> 4;
  const int r0 = blockIdx.x * 64;
  const int c0 = blockIdx.y * 64;

  float acc[4][4] = {};

  const int ar = tid >> 3;         // 0..31 (row within tile, +32 second pass)
  const int ak = (tid & 7) * 4;    // 0,4,...,28
  const int wc = (tid & 15) * 4;   // 0..60
  const int wk = tid >> 4;         // 0..15 (+16 second pass)

  const int nch = (Kin + 31) / 32;
  for (int ch = 0; ch < nch; ++ch) {
    const int k0 = ch * 32;
    // stage A (scalar loads: Kin may be 41/78, rows not 16B-aligned)
#pragma unroll
    for (int p = 0; p < 2; ++p) {
      int r = ar + p * 32;
      int grow = r0 + r;
      bool rok = grow < n;
      const float* arow = A + (size_t)grow * Kin;
#pragma unroll
      for (int i = 0; i < 4; ++i) {
        int k = k0 + ak + i;
        As[ak + i][r] = (rok && k < Kin) ? arow[k] : 0.0f;
      }
    }
    // stage W (float4: Kout and c0,wc are multiples of 4)
#pragma unroll
    for (int p = 0; p < 2; ++p) {
      int k = wk + p * 16;
      int gk = k0 + k;
      float4 v = make_float4(0.f, 0.f, 0.f, 0.f);
      if (gk < Kin) v = *(const float4*)&W[(size_t)gk * Kout + c0 + wc];
      *(float4*)&Ws[k][wc] = v;
    }
    __syncthreads();
#pragma unroll
    for (int k = 0; k < 32; ++k) {
      float4 a4 = *(const float4*)&As[k][ty * 4];
      float4 w4 = *(const float4*)&Ws[k][tx * 4];
      acc[0][0] = fmaf(a4.x, w4.x, acc[0][0]);
      acc[0][1] = fmaf(a4.x, w4.y, acc[0][1]);
      acc[0][2] = fmaf(a4.x, w4.z, acc[0][2]);
      acc[0][3] = fmaf(a4.x, w4.w, acc[0][3]);
      acc[1][0] = fmaf(a4.y, w4.x, acc[1][0]);
      acc[1][1] = fmaf(a4.y, w4.y, acc[1][1]);
      acc[1][2] = fmaf(a4.y, w4.z, acc[1][2]);
      acc[1][3] = fmaf(a4.y, w4.w, acc[1][3]);
      acc[2][0] = fmaf(a4.z, w4.x, acc[2][0]);
      acc[2][1] = fmaf(a4.z, w4.y, acc[2][1]);
      acc[2][2] = fmaf(a4.z, w4.z, acc[2][2]);
      acc[2][3] = fmaf(a4.z, w4.w, acc[2][3]);
      acc[3][0] = fmaf(a4.w, w4.x, acc[3][0]);
      acc[3][1] = fmaf(a4.w, w4.y, acc[3][1]);
      acc[3][2] = fmaf(a4.w, w4.z, acc[3][2]);
      acc[3][3] = fmaf(a4.w, w4.w, acc[3][3]);
    }
    __syncthreads();
  }

  // epilogue: bias (+relu)
  float4 bv = *(const float4*)&bias[c0 + tx * 4];
#pragma unroll
  for (int i = 0; i < 4; ++i) {
    acc[i][0] += bv.x; acc[i][1] += bv.y; acc[i][2] += bv.z; acc[i][3] += bv.w;
    if (RELU) {
#pragma unroll
      for (int j = 0; j < 4; ++j) acc[i][j] = fmaxf(acc[i][j], 0.0f);
    }
  }

  if (!POOL) {
#pragma unroll
    for (int i = 0; i < 4; ++i) {
      int row = r0 + ty * 4 + i;
      if (row < n)
        *(float4*)&Y[(size_t)row * ystride + c0 + tx * 4] =
            make_float4(acc[i][0], acc[i][1], acc[i][2], acc[i][3]);
    }
  } else {
    // segment-sum the 64 rows by sorted batch id, few atomics per column
    float (*red)[68] = (float(*)[68])smem;  // 64 x 68 reuse
    __syncthreads();
#pragma unroll
    for (int i = 0; i < 4; ++i)
      *(float4*)&red[ty * 4 + i][tx * 4] =
          make_float4(acc[i][0], acc[i][1], acc[i][2], acc[i][3]);
    __syncthreads();
    int c = tid & 63;
    int q = tid >> 6;  // 4 row-quarters of 16 rows
    float s = 0.0f;
    int cur = -1;
    for (int rr = 0; rr < 16; ++rr) {
      int row = r0 + q * 16 + rr;
      if (row >= n) break;
      int b = batch[row];
      if (b != cur) {
        if (cur >= 0 && s != 0.0f)
          atomicAdd(&Y[(size_t)cur * ystride + colbase + c0 + c], s);
        cur = b; s = 0.0f;
      }
      s += red[q * 16 + rr][c];
    }
    if (cur >= 0 && s != 0.0f)
      atomicAdd(&Y[(size_t)cur * ystride + colbase + c0 + c], s);
  }
}

// pooled[b, colbase+c] /= max(cnt[b],1)
static __global__ void k_pool_div(float* __restrict__ pooled, const float* __restrict__ cnt,
                                  int colbase) {
  int i = blockIdx.x * blockDim.x + threadIdx.x;
  if (i >= 512 * 256) return;
  int b = i >> 8;
  int c = i & 255;
  pooled[b * 512 + colbase + c] /= fmaxf(cnt[b], 1.0f);
}

// out[row] = X[row,:512] . w + b   -- one wave per row
static __global__ void k_out(float* __restrict__ out, const float* __restrict__ X,
                             const float* __restrict__ w, const float* __restrict__ b) {
  int row = blockIdx.x;
  int lane = threadIdx.x;
  float acc = 0.f;
  for (int k = lane; k < 512; k += 64)
    acc = fmaf(X[row * 512 + k], w[k], acc);
#pragma unroll
  for (int off = 32; off; off >>= 1) acc += __shfl_down(acc, off);
  if (lane == 0) out[row] = acc + b[0];
}

// ---------------- launch ----------------

extern "C" void kernel_launch(void* const* d_in, const int* in_sizes, int n_in,
                              void* d_out, int out_size, void* d_ws, size_t ws_size,
                              hipStream_t stream) {
  const float* p_x  = (const float*)d_in[0];
  const int*   p_ei = (const int*)d_in[1];
  const int*   p_bt = (const int*)d_in[2];
  const float* l_x  = (const float*)d_in[3];
  const int*   l_ei = (const int*)d_in[4];
  const int*   l_bt = (const int*)d_in[5];
  const float* pW1 = (const float*)d_in[6],  *pb1 = (const float*)d_in[7];
  const float* pW2 = (const float*)d_in[8],  *pb2 = (const float*)d_in[9];
  const float* pW3 = (const float*)d_in[10], *pb3 = (const float*)d_in[11];
  const float* lW1 = (const float*)d_in[12], *lb1 = (const float*)d_in[13];
  const float* lW2 = (const float*)d_in[14], *lb2 = (const float*)d_in[15];
  const float* lW3 = (const float*)d_in[16], *lb3 = (const float*)d_in[17];
  const float* fc1W = (const float*)d_in[18], *fc1b = (const float*)d_in[19];
  const float* fc2W = (const float*)d_in[20], *fc2b = (const float*)d_in[21];
  const float* oW  = (const float*)d_in[22], *ob  = (const float*)d_in[23];

  const int n_p = in_sizes[2], n_l = in_sizes[5];
  const int E_p = in_sizes[1] / 2, E_l = in_sizes[4] / 2;
  const int IN_P = in_sizes[0] / n_p, IN_L = in_sizes[3] / n_l;   // 41, 78

  char* wsc = (char*)d_ws;
  size_t off = 0;
  auto alloc = [&](size_t bytes) -> void* {
    void* p = wsc + off;
    off = (off + bytes + 255) & ~(size_t)255;
    return p;
  };
  float* dinv_p = (float*)alloc((size_t)n_p * 4);
  float* dinv_l = (float*)alloc((size_t)n_l * 4);
  float* cnt_p  = (float*)alloc(512 * 4);
  float* cnt_l  = (float*)alloc(512 * 4);
  float* pooled = (float*)alloc(512 * 512 * 4);
  float* F      = (float*)alloc((size_t)n_p * 128 * 4);
  float* AG     = (float*)alloc((size_t)n_p * 128 * 4);
  float* fc1o   = F;                 // branches are done before the FC stack
  float* fc2o   = F + 512 * 1024;
  (void)ws_size; (void)n_in; (void)out_size;

  hipMemsetAsync(pooled, 0, 512 * 512 * 4, stream);
  hipMemsetAsync(cnt_p, 0, 512 * 4, stream);
  hipMemsetAsync(cnt_l, 0, 512 * 4, stream);

  auto gemm = [&](bool relu, bool pool, const float* A, const float* W, const float* b,
                  float* Y, int n, int Kin, int Kout, const int* batch, int ystride,
                  int colbase) {
    dim3 g((n + 63) / 64, Kout / 64);
    if (pool)
      k_gemm_t<true, true><<<g, 256, 0, stream>>>(A, W, b, Y, n, Kin, Kout, batch, ystride, colbase);
    else if (relu)
      k_gemm_t<true, false><<<g, 256, 0, stream>>>(A, W, b, Y, n, Kin, Kout, nullptr, ystride, 0);
    else
      k_gemm_t<false, false><<<g, 256, 0, stream>>>(A, W, b, Y, n, Kin, Kout, nullptr, ystride, 0);
  };

  auto branch = [&](const float* x0, const int* ei, const int* batch, int n, int E, int IN,
                    const float* W1, const float* b1, const float* W2, const float* b2,
                    const float* W3, const float* b3, float* dinv, float* cnt, int colbase) {
    const int* src = ei;
    const int* dst = ei + E;
    k_fill<<<(n + 255) / 256, 256, 0, stream>>>(dinv, 1.0f, n);
    k_deg<<<(E + 255) / 256, 256, 0, stream>>>(dinv, dst, E);
    k_rsqrt<<<(n + 255) / 256, 256, 0, stream>>>(dinv, n);
    k_count<<<(n + 255) / 256, 256, 0, stream>>>(cnt, batch, n);
    // layer 1: AG = A_hat x0 ; F = relu(AG @ W1 + b1)   [n x 64]
    int tot = n * IN;
    k_self_init<<<(tot + 255) / 256, 256, 0, stream>>>(AG, x0, dinv, n, IN);
    k_edge_scatter<<<E, (IN + 63) / 64 * 64, 0, stream>>>(AG, x0, src, dst, dinv, E, IN);
    gemm(true, false, AG, W1, b1, F, n, IN, 64, nullptr, 64, 0);
    // layer 2
    tot = n * 64;
    k_self_init<<<(tot + 255) / 256, 256, 0, stream>>>(AG, F, dinv, n, 64);
    k_edge_scatter<<<E, 64, 0, stream>>>(AG, F, src, dst, dinv, E, 64);
    gemm(true, false, AG, W2, b2, F, n, 64, 128, nullptr, 128, 0);
    // layer 3: fused mean-pool numerator into pooled
    tot = n * 128;
    k_self_init<<<(tot + 255) / 256, 256, 0, stream>>>(AG, F, dinv, n, 128);
    k_edge_scatter<<<E, 128, 0, stream>>>(AG, F, src, dst, dinv, E, 128);
    gemm(true, true, AG, W3, b3, pooled, n, 128, 256, batch, 512, colbase);
  };

  branch(p_x, p_ei, p_bt, n_p, E_p, IN_P, pW1, pb1, pW2, pb2, pW3, pb3, dinv_p, cnt_p, 0);
  branch(l_x, l_ei, l_bt, n_l, E_l, IN_L, lW1, lb1, lW2, lb2, lW3, lb3, dinv_l, cnt_l, 256);

  k_pool_div<<<(512 * 256 + 255) / 256, 256, 0, stream>>>(pooled, cnt_p, 0);
  k_pool_div<<<(512 * 256 + 255) / 256, 256, 0, stream>>>(pooled, cnt_l, 256);

  // FC stack
  gemm(true, false, pooled, fc1W, fc1b, fc1o, 512, 512, 1024, nullptr, 1024, 0);
  gemm(true, false, fc1o, fc2W, fc2b, fc2o, 512, 1024, 512, nullptr, 512, 0);
  k_out<<<512, 64, 0, stream>>>((float*)d_out, fc2o, oW, ob);
}

// Round 4
// 1913.883 us; speedup vs baseline: 3.5164x; 1.2556x over previous
//
#include <hip/hip_runtime.h>

// ---------------- small helper kernels ----------------

static __global__ void k_fill(float* __restrict__ p, float v, int n) {
  int i = blockIdx.x * blockDim.x + threadIdx.x;
  if (i < n) p[i] = v;
}

static __global__ void k_deg(float* __restrict__ deg, const int* __restrict__ dst, int E) {
  int e = blockIdx.x * blockDim.x + threadIdx.x;
  if (e < E) atomicAdd(&deg[dst[e]], 1.0f);
}

static __global__ void k_rsqrt(float* __restrict__ d, int n) {
  int i = blockIdx.x * blockDim.x + threadIdx.x;
  if (i < n) d[i] = 1.0f / sqrtf(d[i]);
}

static __global__ void k_count(float* __restrict__ cnt, const int* __restrict__ batch, int n) {
  int i = blockIdx.x * blockDim.x + threadIdx.x;
  if (i < n) atomicAdd(&cnt[batch[i]], 1.0f);
}

// ---------------- CSR build (indegree scan + position fill) ----------------

// per-block exclusive scan of indegree (= degf-1); ex[i] within-block exclusive, bsum[b] block total
static __global__ void k_scan1(const float* __restrict__ degf, int* __restrict__ ex,
                               int* __restrict__ bsum, int n) {
  __shared__ int sm[256];
  int i = blockIdx.x * 256 + threadIdx.x;
  int v = (i < n) ? ((int)degf[i] - 1) : 0;
  sm[threadIdx.x] = v;
  __syncthreads();
  for (int off = 1; off < 256; off <<= 1) {
    int t = (threadIdx.x >= (unsigned)off) ? sm[threadIdx.x - off] : 0;
    __syncthreads();
    sm[threadIdx.x] += t;
    __syncthreads();
  }
  if (i < n) ex[i] = sm[threadIdx.x] - v;
  if (threadIdx.x == 255) bsum[blockIdx.x] = sm[255];
}

// single-block inclusive scan of bsum[nb] with carry across 1024-chunks
static __global__ void k_scan2(int* __restrict__ bsum, int nb) {
  __shared__ int sm[1024];
  __shared__ int carry;
  if (threadIdx.x == 0) carry = 0;
  __syncthreads();
  for (int base = 0; base < nb; base += 1024) {
    int i = base + threadIdx.x;
    int v = (i < nb) ? bsum[i] : 0;
    sm[threadIdx.x] = v;
    __syncthreads();
    for (int off = 1; off < 1024; off <<= 1) {
      int t = (threadIdx.x >= (unsigned)off) ? sm[threadIdx.x - off] : 0;
      __syncthreads();
      sm[threadIdx.x] += t;
      __syncthreads();
    }
    if (i < nb) bsum[i] = sm[threadIdx.x] + carry;
    __syncthreads();
    if (threadIdx.x == 0) carry += sm[1023];
    __syncthreads();
  }
}

// rowptr[i] = cursor_ex[i] + block_offset ; cursor gets the same (fill cursor); rowptr[n] = E
static __global__ void k_scan3(int* __restrict__ rowptr, int* __restrict__ cursor_ex,
                               const int* __restrict__ bsum, int n, int E) {
  int i = blockIdx.x * 256 + threadIdx.x;
  if (i > n) return;
  if (i == n) { rowptr[n] = E; return; }
  int add = blockIdx.x ? bsum[blockIdx.x - 1] : 0;
  int r = cursor_ex[i] + add;
  rowptr[i] = r;
  cursor_ex[i] = r;
}

// esrc[pos] = src, grouped by dst via atomic cursor
static __global__ void k_fill_csr(const int* __restrict__ src, const int* __restrict__ dst,
                                  int* __restrict__ cursor, int* __restrict__ esrc, int E) {
  int e = blockIdx.x * 256 + threadIdx.x;
  if (e >= E) return;
  int pos = atomicAdd(&cursor[dst[e]], 1);
  esrc[pos] = src[e];
}

// ---------------- pull aggregation (fused self term, no atomics) ----------------
// AG[i,:] = dinv[i]^2 * X[i,:] + sum_{s in in(i)} dinv[s]*dinv[i] * X[s,:]
// one 64-lane wave per node, k strided by 64 (K <= 128)
static __global__ void __launch_bounds__(256)
k_agg(float* __restrict__ AG, const float* __restrict__ X,
      const int* __restrict__ rowptr, const int* __restrict__ esrc,
      const float* __restrict__ dinv, int n, int K) {
  int wid = (blockIdx.x * blockDim.x + threadIdx.x) >> 6;
  int lane = threadIdx.x & 63;
  if (wid >= n) return;
  int rs = rowptr[wid], re = rowptr[wid + 1];
  float dv = dinv[wid];
  const float* xr = X + (size_t)wid * K;
  float a0 = (lane < K) ? xr[lane] * dv * dv : 0.0f;
  float a1 = (64 + lane < K) ? xr[64 + lane] * dv * dv : 0.0f;
  for (int e = rs; e < re; ++e) {
    int s = esrc[e];
    float w = dinv[s] * dv;
    const float* xs = X + (size_t)s * K;
    if (lane < K) a0 = fmaf(xs[lane], w, a0);
    if (64 + lane < K) a1 = fmaf(xs[64 + lane], w, a1);
  }
  float* ar = AG + (size_t)wid * K;
  if (lane < K) ar[lane] = a0;
  if (64 + lane < K) ar[64 + lane] = a1;
}

// ---------------- tiled GEMM ----------------
// Y = [relu](A @ W + b).  Tile 64x64, 256 threads, 4x4 per thread, K-chunk 32.
// POOL: segment-sum rows by (sorted) batch and atomicAdd the per-block partials.
template<bool RELU, bool POOL>
static __global__ void __launch_bounds__(256)
k_gemm_t(const float* __restrict__ A, const float* __restrict__ W,
         const float* __restrict__ bias, float* __restrict__ Y,
         int n, int Kin, int Kout,
         const int* __restrict__ batch, int ystride, int colbase) {
  __shared__ float smem[2 * 32 * 68];
  float (*As)[68] = (float(*)[68])smem;             // As[k][row] (transposed)
  float (*Ws)[68] = (float(*)[68])(smem + 32 * 68); // Ws[k][col]

  const int tid = threadIdx.x;
  const int tx = tid & 15, ty = tid >> 4;
  const int r0 = blockIdx.x * 64;
  const int c0 = blockIdx.y * 64;

  float acc[4][4] = {};

  const int ar = tid >> 3;         // 0..31 (row within tile, +32 second pass)
  const int ak = (tid & 7) * 4;    // 0,4,...,28
  const int wc = (tid & 15) * 4;   // 0..60
  const int wk = tid >> 4;         // 0..15 (+16 second pass)

  const int nch = (Kin + 31) / 32;
  for (int ch = 0; ch < nch; ++ch) {
    const int k0 = ch * 32;
#pragma unroll
    for (int p = 0; p < 2; ++p) {
      int r = ar + p * 32;
      int grow = r0 + r;
      bool rok = grow < n;
      const float* arow = A + (size_t)grow * Kin;
#pragma unroll
      for (int i = 0; i < 4; ++i) {
        int k = k0 + ak + i;
        As[ak + i][r] = (rok && k < Kin) ? arow[k] : 0.0f;
      }
    }
#pragma unroll
    for (int p = 0; p < 2; ++p) {
      int k = wk + p * 16;
      int gk = k0 + k;
      float4 v = make_float4(0.f, 0.f, 0.f, 0.f);
      if (gk < Kin) v = *(const float4*)&W[(size_t)gk * Kout + c0 + wc];
      *(float4*)&Ws[k][wc] = v;
    }
    __syncthreads();
#pragma unroll
    for (int k = 0; k < 32; ++k) {
      float4 a4 = *(const float4*)&As[k][ty * 4];
      float4 w4 = *(const float4*)&Ws[k][tx * 4];
      acc[0][0] = fmaf(a4.x, w4.x, acc[0][0]);
      acc[0][1] = fmaf(a4.x, w4.y, acc[0][1]);
      acc[0][2] = fmaf(a4.x, w4.z, acc[0][2]);
      acc[0][3] = fmaf(a4.x, w4.w, acc[0][3]);
      acc[1][0] = fmaf(a4.y, w4.x, acc[1][0]);
      acc[1][1] = fmaf(a4.y, w4.y, acc[1][1]);
      acc[1][2] = fmaf(a4.y, w4.z, acc[1][2]);
      acc[1][3] = fmaf(a4.y, w4.w, acc[1][3]);
      acc[2][0] = fmaf(a4.z, w4.x, acc[2][0]);
      acc[2][1] = fmaf(a4.z, w4.y, acc[2][1]);
      acc[2][2] = fmaf(a4.z, w4.z, acc[2][2]);
      acc[2][3] = fmaf(a4.z, w4.w, acc[2][3]);
      acc[3][0] = fmaf(a4.w, w4.x, acc[3][0]);
      acc[3][1] = fmaf(a4.w, w4.y, acc[3][1]);
      acc[3][2] = fmaf(a4.w, w4.z, acc[3][2]);
      acc[3][3] = fmaf(a4.w, w4.w, acc[3][3]);
    }
    __syncthreads();
  }

  float4 bv = *(const float4*)&bias[c0 + tx * 4];
#pragma unroll
  for (int i = 0; i < 4; ++i) {
    acc[i][0] += bv.x; acc[i][1] += bv.y; acc[i][2] += bv.z; acc[i][3] += bv.w;
    if (RELU) {
#pragma unroll
      for (int j = 0; j < 4; ++j) acc[i][j] = fmaxf(acc[i][j], 0.0f);
    }
  }

  if (!POOL) {
#pragma unroll
    for (int i = 0; i < 4; ++i) {
      int row = r0 + ty * 4 + i;
      if (row < n)
        *(float4*)&Y[(size_t)row * ystride + c0 + tx * 4] =
            make_float4(acc[i][0], acc[i][1], acc[i][2], acc[i][3]);
    }
  } else {
    float (*red)[68] = (float(*)[68])smem;  // 64 x 68 reuse
    __syncthreads();
#pragma unroll
    for (int i = 0; i < 4; ++i)
      *(float4*)&red[ty * 4 + i][tx * 4] =
          make_float4(acc[i][0], acc[i][1], acc[i][2], acc[i][3]);
    __syncthreads();
    int c = tid & 63;
    int q = tid >> 6;  // 4 row-quarters of 16 rows
    float s = 0.0f;
    int cur = -1;
    for (int rr = 0; rr < 16; ++rr) {
      int row = r0 + q * 16 + rr;
      if (row >= n) break;
      int b = batch[row];
      if (b != cur) {
        if (cur >= 0 && s != 0.0f)
          atomicAdd(&Y[(size_t)cur * ystride + colbase + c0 + c], s);
        cur = b; s = 0.0f;
      }
      s += red[q * 16 + rr][c];
    }
    if (cur >= 0 && s != 0.0f)
      atomicAdd(&Y[(size_t)cur * ystride + colbase + c0 + c], s);
  }
}

// pooled[b, colbase+c] /= max(cnt[b],1)
static __global__ void k_pool_div(float* __restrict__ pooled, const float* __restrict__ cnt,
                                  int colbase) {
  int i = blockIdx.x * blockDim.x + threadIdx.x;
  if (i >= 512 * 256) return;
  int b = i >> 8;
  int c = i & 255;
  pooled[b * 512 + colbase + c] /= fmaxf(cnt[b], 1.0f);
}

// out[row] = X[row,:512] . w + b   -- one wave per row
static __global__ void k_out(float* __restrict__ out, const float* __restrict__ X,
                             const float* __restrict__ w, const float* __restrict__ b) {
  int row = blockIdx.x;
  int lane = threadIdx.x;
  float acc = 0.f;
  for (int k = lane; k < 512; k += 64)
    acc = fmaf(X[row * 512 + k], w[k], acc);
#pragma unroll
  for (int off = 32; off; off >>= 1) acc += __shfl_down(acc, off);
  if (lane == 0) out[row] = acc + b[0];
}

// ---------------- launch ----------------

extern "C" void kernel_launch(void* const* d_in, const int* in_sizes, int n_in,
                              void* d_out, int out_size, void* d_ws, size_t ws_size,
                              hipStream_t stream) {
  const float* p_x  = (const float*)d_in[0];
  const int*   p_ei = (const int*)d_in[1];
  const int*   p_bt = (const int*)d_in[2];
  const float* l_x  = (const float*)d_in[3];
  const int*   l_ei = (const int*)d_in[4];
  const int*   l_bt = (const int*)d_in[5];
  const float* pW1 = (const float*)d_in[6],  *pb1 = (const float*)d_in[7];
  const float* pW2 = (const float*)d_in[8],  *pb2 = (const float*)d_in[9];
  const float* pW3 = (const float*)d_in[10], *pb3 = (const float*)d_in[11];
  const float* lW1 = (const float*)d_in[12], *lb1 = (const float*)d_in[13];
  const float* lW2 = (const float*)d_in[14], *lb2 = (const float*)d_in[15];
  const float* lW3 = (const float*)d_in[16], *lb3 = (const float*)d_in[17];
  const float* fc1W = (const float*)d_in[18], *fc1b = (const float*)d_in[19];
  const float* fc2W = (const float*)d_in[20], *fc2b = (const float*)d_in[21];
  const float* oW  = (const float*)d_in[22], *ob  = (const float*)d_in[23];

  const int n_p = in_sizes[2], n_l = in_sizes[5];
  const int E_p = in_sizes[1] / 2, E_l = in_sizes[4] / 2;
  const int IN_P = in_sizes[0] / n_p, IN_L = in_sizes[3] / n_l;   // 41, 78

  char* wsc = (char*)d_ws;
  size_t off = 0;
  auto alloc = [&](size_t bytes) -> void* {
    void* p = wsc + off;
    off = (off + bytes + 255) & ~(size_t)255;
    return p;
  };
  float* dinv_p = (float*)alloc((size_t)n_p * 4);   // doubles as degf before rsqrt
  float* dinv_l = (float*)alloc((size_t)n_l * 4);
  float* cnt_p  = (float*)alloc(512 * 4);
  float* cnt_l  = (float*)alloc(512 * 4);
  float* pooled = (float*)alloc(512 * 512 * 4);
  float* F      = (float*)alloc((size_t)n_p * 128 * 4);
  float* AG     = (float*)alloc((size_t)n_p * 128 * 4);
  int* bsum     = (int*)alloc(1024 * 4);
  int* cur_p    = (int*)alloc((size_t)n_p * 4);      // ex/cursor
  int* row_p    = (int*)alloc(((size_t)n_p + 1) * 4);
  int* esrc_p   = (int*)alloc((size_t)E_p * 4);
  int* cur_l    = (int*)alloc((size_t)n_l * 4);
  int* row_l    = (int*)alloc(((size_t)n_l + 1) * 4);
  int* esrc_l   = (int*)alloc((size_t)E_l * 4);
  float* fc1o   = F;                 // branches are done before the FC stack
  float* fc2o   = F + 512 * 1024;
  (void)ws_size; (void)n_in; (void)out_size;

  hipMemsetAsync(pooled, 0, 512 * 512 * 4, stream);
  hipMemsetAsync(cnt_p, 0, 512 * 4, stream);
  hipMemsetAsync(cnt_l, 0, 512 * 4, stream);

  auto gemm = [&](bool relu, bool pool, const float* A, const float* W, const float* b,
                  float* Y, int n, int Kin, int Kout, const int* batch, int ystride,
                  int colbase) {
    dim3 g((n + 63) / 64, Kout / 64);
    if (pool)
      k_gemm_t<true, true><<<g, 256, 0, stream>>>(A, W, b, Y, n, Kin, Kout, batch, ystride, colbase);
    else if (relu)
      k_gemm_t<true, false><<<g, 256, 0, stream>>>(A, W, b, Y, n, Kin, Kout, nullptr, ystride, 0);
    else
      k_gemm_t<false, false><<<g, 256, 0, stream>>>(A, W, b, Y, n, Kin, Kout, nullptr, ystride, 0);
  };

  auto branch = [&](const float* x0, const int* ei, const int* batch, int n, int E, int IN,
                    const float* W1, const float* b1, const float* W2, const float* b2,
                    const float* W3, const float* b3, float* dinv, float* cnt,
                    int* cursor, int* rowptr, int* esrc, int colbase) {
    const int* src = ei;
    const int* dst = ei + E;
    const int nb = (n + 255) / 256;
    // degree (float; = 1 + indeg) and pool counts
    k_fill<<<nb, 256, 0, stream>>>(dinv, 1.0f, n);
    k_deg<<<(E + 255) / 256, 256, 0, stream>>>(dinv, dst, E);
    k_count<<<nb, 256, 0, stream>>>(cnt, batch, n);
    // CSR: exclusive scan of indeg, then position fill
    k_scan1<<<nb, 256, 0, stream>>>(dinv, cursor, bsum, n);
    k_scan2<<<1, 1024, 0, stream>>>(bsum, nb);
    k_scan3<<<(n + 256) / 256 + 1, 256, 0, stream>>>(rowptr, cursor, bsum, n, E);
    k_rsqrt<<<nb, 256, 0, stream>>>(dinv, n);
    k_fill_csr<<<(E + 255) / 256, 256, 0, stream>>>(src, dst, cursor, esrc, E);
    // layer 1
    int gw = (n * 64 + 255) / 256;
    k_agg<<<gw, 256, 0, stream>>>(AG, x0, rowptr, esrc, dinv, n, IN);
    gemm(true, false, AG, W1, b1, F, n, IN, 64, nullptr, 64, 0);
    // layer 2
    k_agg<<<gw, 256, 0, stream>>>(AG, F, rowptr, esrc, dinv, n, 64);
    gemm(true, false, AG, W2, b2, F, n, 64, 128, nullptr, 128, 0);
    // layer 3: fused mean-pool numerator into pooled
    k_agg<<<gw, 256, 0, stream>>>(AG, F, rowptr, esrc, dinv, n, 128);
    gemm(true, true, AG, W3, b3, pooled, n, 128, 256, batch, 512, colbase);
  };

  branch(p_x, p_ei, p_bt, n_p, E_p, IN_P, pW1, pb1, pW2, pb2, pW3, pb3,
         dinv_p, cnt_p, cur_p, row_p, esrc_p, 0);
  branch(l_x, l_ei, l_bt, n_l, E_l, IN_L, lW1, lb1, lW2, lb2, lW3, lb3,
         dinv_l, cnt_l, cur_l, row_l, esrc_l, 256);

  k_pool_div<<<(512 * 256 + 255) / 256, 256, 0, stream>>>(pooled, cnt_p, 0);
  k_pool_div<<<(512 * 256 + 255) / 256, 256, 0, stream>>>(pooled, cnt_l, 256);

  // FC stack
  gemm(true, false, pooled, fc1W, fc1b, fc1o, 512, 512, 1024, nullptr, 1024, 0);
  gemm(true, false, fc1o, fc2W, fc2b, fc2o, 512, 1024, 512, nullptr, 512, 0);
  k_out<<<512, 64, 0, stream>>>((float*)d_out, fc2o, oW, ob);
}